// Round 1
// baseline (324.454 us; speedup 1.0000x reference)
//
#include <hip/hip_runtime.h>
#include <stdint.h>

typedef int v4i __attribute__((ext_vector_type(4)));

// direct global->LDS DMA, 16B per lane. LDS dest = wave-uniform base + lane*16.
__device__ __forceinline__ void gll16(const void* g, void* l) {
    __builtin_amdgcn_global_load_lds(
        (const __attribute__((address_space(1))) void*)(uintptr_t)g,
        (__attribute__((address_space(3))) void*)(uint32_t)(uintptr_t)l,
        16, 0, 0);
}

// ---------------- Kernel 1: per-row dynamic int8 quantization of x ----------------
__global__ __launch_bounds__(256) void quant_x(const float* __restrict__ x,
                                               signed char* __restrict__ xq,
                                               float* __restrict__ sx, int M) {
    const int row = blockIdx.x;
    const int tid = threadIdx.x;
    signed char* qrow = xq + (size_t)row * 1024;
    if (row >= M) {  // zero the pad rows (uniform branch per block)
        ((char4*)qrow)[tid] = make_char4(0, 0, 0, 0);
        if (tid == 0) sx[row] = 0.0f;
        return;
    }
    const float4 v = ((const float4*)(x + (size_t)row * 1024))[tid];
    float a = fmaxf(fmaxf(fabsf(v.x), fabsf(v.y)), fmaxf(fabsf(v.z), fabsf(v.w)));
#pragma unroll
    for (int off = 32; off > 0; off >>= 1)
        a = fmaxf(a, __shfl_xor(a, off));
    __shared__ float red[4];
    if ((tid & 63) == 0) red[tid >> 6] = a;
    __syncthreads();
    const float am = fmaxf(fmaxf(red[0], red[1]), fmaxf(red[2], red[3]));
    const float amc = fmaxf(am, 1e-8f);
    const float scale = amc * (1.0f / 127.0f);
    const float inv = 127.0f / amc;
    char4 q;
    q.x = (signed char)(int)rintf(v.x * inv);
    q.y = (signed char)(int)rintf(v.y * inv);
    q.z = (signed char)(int)rintf(v.z * inv);
    q.w = (signed char)(int)rintf(v.w * inv);
    ((char4*)qrow)[tid] = q;
    if (tid == 0) sx[row] = scale;
}

// ---------------- Kernel 2: w_int (int32, values in [-127,127]) -> int8 ----------------
__global__ __launch_bounds__(256) void conv_w(const int* __restrict__ w,
                                              signed char* __restrict__ w8, int n4) {
    const int i = blockIdx.x * 256 + threadIdx.x;
    if (i < n4) {
        const int4 v = ((const int4*)w)[i];
        char4 c;
        c.x = (signed char)v.x; c.y = (signed char)v.y;
        c.z = (signed char)v.z; c.w = (signed char)v.w;
        ((char4*)w8)[i] = c;
    }
}

// ---------------- Kernel 3: int8 GEMM, 256x256 tile, deep-pipelined ----------------
// 8 waves (2M x 4N), each wave owns a 128x64 output subtile = 8x4 grid of 16x16x64
// i8 MFMAs. BK = 64 bytes of K per tile, NT = K/64 tiles.
//
// Schedule (T3+T4+T5 port, plain HIP):
//   LDS double-buffered (2 x (16KB A + 16KB B)); prefetch runs 2 K-tiles ahead.
//   Per K-tile T (buffer cur = T&1):
//     ph0: ds_read all 12 frags (8 A + 4 B) | B1 | lgkmcnt(0) | setprio(1) 16 MFMA | B2
//     ph1: stage tile T+2 into buf[cur] (4 x gll16) | setprio(1) 16 MFMA |
//          s_waitcnt vmcnt(4) (counted, NOT 0) | B3
//   Safety: tile-T frag reads complete before B2 (lgkmcnt(0) precedes MFMA-1), so the
//   T+2 stage overwrite after B2 is race-free; vmcnt(4) at end of T+1 retires T+2's
//   loads (only T+3's 4 may remain) before B3 releases the reads. Tail tiles where the
//   T+2 stage is skipped use vmcnt(0) to keep the count exact.
//
// LDS swizzle (kept from verified 128^2 kernel): row r stores its four 16B chunks
// permuted by key=(r>>1)&3; applied on the GLOBAL fetch address (gll16 cannot
// scatter), un-applied on fragment reads -> free 2-way bank conflicts.
__global__ __launch_bounds__(512, 2) void gemm_i8(const signed char* __restrict__ xq,
                                                  const signed char* __restrict__ w8,
                                                  const float* __restrict__ sx,
                                                  const float* __restrict__ sw,
                                                  const float* __restrict__ bias,
                                                  float* __restrict__ out,
                                                  int M, int N, int K) {
    __shared__ signed char As[2][16384];   // 256 rows x 64B
    __shared__ signed char Bs[2][16384];

    const int tid  = threadIdx.x;
    const int lane = tid & 63;
    const int wave = tid >> 6;
    const int m_off = (wave >> 2) * 128;   // 2 waves in M
    const int n_off = (wave & 3) * 64;     // 4 waves in N
    const int m_block = blockIdx.y * 256;
    const int n_block = blockIdx.x * 256;
    const int nt_tiles = K >> 6;           // K/64

    v4i acc[8][4];
#pragma unroll
    for (int mt = 0; mt < 8; ++mt)
#pragma unroll
        for (int nt = 0; nt < 4; ++nt) {
            acc[mt][nt].x = 0; acc[mt][nt].y = 0; acc[mt][nt].z = 0; acc[mt][nt].w = 0;
        }

    // staging map: thread t -> LDS slot (row t>>2, chunk t&3) of a 128-row unit;
    // fetches swizzled global chunk (t&3)^((t>>3)&3). Key invariant under +128 rows.
    const int sc = ((tid & 3) ^ ((tid >> 3) & 3)) * 16;
    const signed char* sA = xq + (size_t)(m_block + (tid >> 2)) * K + sc;
    const signed char* sB = w8 + (size_t)(n_block + (tid >> 2)) * K + sc;

    auto stage = [&](int Tt, int bufi) {
        const size_t ko = (size_t)Tt << 6;
        gll16(sA + ko,                    &As[bufi][wave * 1024]);
        gll16(sA + ko + ((size_t)K << 7), &As[bufi][wave * 1024 + 8192]);  // rows +128
        gll16(sB + ko,                    &Bs[bufi][wave * 1024]);
        gll16(sB + ko + ((size_t)K << 7), &Bs[bufi][wave * 1024 + 8192]);
    };

    // fragment read: lane reads row (lane&15), global chunk (lane>>4); un-swizzle.
    const int fr = lane & 15;
    const int off_frag = fr * 64 + (((lane >> 4) ^ ((fr >> 1) & 3)) * 16);

    // prologue: T0 -> buf0, T1 -> buf1; wait T0 resident (T1's 4 stay in flight)
    stage(0, 0);
    stage(1, 1);
    asm volatile("s_waitcnt vmcnt(4)" ::: "memory");
    __builtin_amdgcn_s_barrier();

    for (int T = 0; T < nt_tiles; ++T) {
        const int cur = T & 1;
        v4i af[8], bf[4];
        const signed char* Ab = &As[cur][m_off * 64 + off_frag];
        const signed char* Bb = &Bs[cur][n_off * 64 + off_frag];
#pragma unroll
        for (int mt = 0; mt < 8; ++mt) af[mt] = *(const v4i*)(Ab + mt * 1024);
#pragma unroll
        for (int nt = 0; nt < 4; ++nt) bf[nt] = *(const v4i*)(Bb + nt * 1024);

        __builtin_amdgcn_s_barrier();                        // B1: phase-align waves
        asm volatile("s_waitcnt lgkmcnt(0)" ::: "memory");   // all 12 reads landed
        __builtin_amdgcn_s_setprio(1);
#pragma unroll
        for (int mt = 0; mt < 4; ++mt)
#pragma unroll
            for (int nt = 0; nt < 4; ++nt)
                acc[mt][nt] = __builtin_amdgcn_mfma_i32_16x16x64_i8(af[mt], bf[nt], acc[mt][nt], 0, 0, 0);
        __builtin_amdgcn_s_setprio(0);
        __builtin_amdgcn_s_barrier();                        // B2: all waves' reads done

        if (T + 2 < nt_tiles) stage(T + 2, cur);             // overwrite own buffer: safe past B2

        __builtin_amdgcn_s_setprio(1);
#pragma unroll
        for (int mt = 4; mt < 8; ++mt)
#pragma unroll
            for (int nt = 0; nt < 4; ++nt)
                acc[mt][nt] = __builtin_amdgcn_mfma_i32_16x16x64_i8(af[mt], bf[nt], acc[mt][nt], 0, 0, 0);
        __builtin_amdgcn_s_setprio(0);

        if (T + 1 < nt_tiles) {
            if (T + 2 < nt_tiles)
                asm volatile("s_waitcnt vmcnt(4)" ::: "memory");  // T+1 resident; T+2 in flight
            else
                asm volatile("s_waitcnt vmcnt(0)" ::: "memory");  // tail: no newer loads exist
            __builtin_amdgcn_s_barrier();                    // B3: tile boundary
        }
    }

    // epilogue: C/D layout col=lane&15, row=(lane>>4)*4+reg (dtype-independent)
    const int lr = lane >> 4;
    const int lc = lane & 15;
#pragma unroll
    for (int mt = 0; mt < 8; ++mt) {
        const int rbase = m_block + m_off + mt * 16 + lr * 4;
        float sxv[4];
#pragma unroll
        for (int r = 0; r < 4; ++r) sxv[r] = sx[rbase + r];  // pad rows have sx=0
#pragma unroll
        for (int nt = 0; nt < 4; ++nt) {
            const int col = n_block + n_off + nt * 16 + lc;
            const float swv = sw[col];
            const float bv  = bias[col];
            const int* a = (const int*)&acc[mt][nt];
#pragma unroll
            for (int r = 0; r < 4; ++r) {
                const int row = rbase + r;
                if (row < M)
                    out[(size_t)row * N + col] = (float)a[r] * sxv[r] * swv + bv;
            }
        }
    }
}

extern "C" void kernel_launch(void* const* d_in, const int* in_sizes, int n_in,
                              void* d_out, int out_size, void* d_ws, size_t ws_size,
                              hipStream_t stream) {
    const float* x       = (const float*)d_in[0];
    const int*   w_int   = (const int*)d_in[1];
    const float* scale_w = (const float*)d_in[2];
    const float* bias    = (const float*)d_in[3];
    float* out = (float*)d_out;

    const int D_OUT = in_sizes[2];             // 2560
    const int D_IN  = in_sizes[1] / D_OUT;     // 1024
    const int M     = in_sizes[0] / D_IN;      // 18464
    const int Mpad  = ((M + 255) / 256) * 256; // 18688

    // workspace layout (all 16B-aligned):
    signed char* xq = (signed char*)d_ws;                      // Mpad * D_IN  int8
    signed char* w8 = xq + (size_t)Mpad * D_IN;                // D_OUT * D_IN int8
    float*       sx = (float*)(w8 + (size_t)D_OUT * D_IN);     // Mpad floats

    quant_x<<<Mpad, 256, 0, stream>>>(x, xq, sx, M);
    const int n4 = D_OUT * D_IN / 4;
    conv_w<<<(n4 + 255) / 256, 256, 0, stream>>>(w_int, w8, n4);
    dim3 grid(D_OUT / 256, Mpad / 256);  // (10, 73): x-major sweeps N for one M-panel -> A-tile L2 reuse
    gemm_i8<<<grid, dim3(512, 1, 1), 0, stream>>>(xq, w8, sx, scale_w, bias, out, M, D_OUT, D_IN);
}

// Round 2
// 315.101 us; speedup vs baseline: 1.0297x; 1.0297x over previous
//
#include <hip/hip_runtime.h>
#include <stdint.h>

typedef int v4i  __attribute__((ext_vector_type(4)));
typedef int v16i __attribute__((ext_vector_type(16)));

// direct global->LDS DMA, 16B per lane. LDS dest = wave-uniform base + lane*16.
__device__ __forceinline__ void gll16(const void* g, void* l) {
    __builtin_amdgcn_global_load_lds(
        (const __attribute__((address_space(1))) void*)(uintptr_t)g,
        (__attribute__((address_space(3))) void*)(uint32_t)(uintptr_t)l,
        16, 0, 0);
}

// ---------------- Kernel 1: per-row dynamic int8 quantization of x ----------------
__global__ __launch_bounds__(256) void quant_x(const float* __restrict__ x,
                                               signed char* __restrict__ xq,
                                               float* __restrict__ sx, int M) {
    const int row = blockIdx.x;
    const int tid = threadIdx.x;
    signed char* qrow = xq + (size_t)row * 1024;
    if (row >= M) {  // zero the pad rows (uniform branch per block)
        ((char4*)qrow)[tid] = make_char4(0, 0, 0, 0);
        if (tid == 0) sx[row] = 0.0f;
        return;
    }
    const float4 v = ((const float4*)(x + (size_t)row * 1024))[tid];
    float a = fmaxf(fmaxf(fabsf(v.x), fabsf(v.y)), fmaxf(fabsf(v.z), fabsf(v.w)));
#pragma unroll
    for (int off = 32; off > 0; off >>= 1)
        a = fmaxf(a, __shfl_xor(a, off));
    __shared__ float red[4];
    if ((tid & 63) == 0) red[tid >> 6] = a;
    __syncthreads();
    const float am = fmaxf(fmaxf(red[0], red[1]), fmaxf(red[2], red[3]));
    const float amc = fmaxf(am, 1e-8f);
    const float scale = amc * (1.0f / 127.0f);
    const float inv = 127.0f / amc;
    char4 q;
    q.x = (signed char)(int)rintf(v.x * inv);
    q.y = (signed char)(int)rintf(v.y * inv);
    q.z = (signed char)(int)rintf(v.z * inv);
    q.w = (signed char)(int)rintf(v.w * inv);
    ((char4*)qrow)[tid] = q;
    if (tid == 0) sx[row] = scale;
}

// ---------------- Kernel 2: w_int (int32, values in [-127,127]) -> int8 ----------------
__global__ __launch_bounds__(256) void conv_w(const int* __restrict__ w,
                                              signed char* __restrict__ w8, int n4) {
    const int i = blockIdx.x * 256 + threadIdx.x;
    if (i < n4) {
        const int4 v = ((const int4*)w)[i];
        char4 c;
        c.x = (signed char)v.x; c.y = (signed char)v.y;
        c.z = (signed char)v.z; c.w = (signed char)v.w;
        ((char4*)w8)[i] = c;
    }
}

// ---------------- Kernel 3: int8 GEMM, 128x128 tile, k-step pipelined ----------------
// 4 waves, each owns a 64x64 output subtile = 2x2 grid of 32x32x32 i8 MFMAs.
// BK = 64 bytes of K per tile (2 k-steps of 32), NT = K/64 tiles.
//
// Pipeline:
//   LDS double-buffered (2 x (8KB A + 8KB B) = 32KB); global prefetch 2 tiles ahead
//   with counted s_waitcnt vmcnt(4) (never 0 mid-loop).
//   Per tile T: { ds_read ks1 frags | MFMA ks0 } -> lgkm(0)+B1 -> stage(T+2) ->
//               vmcnt(4)+B2 -> { ds_read T+1 ks0 frags | MFMA ks1 }.
//   Every MFMA group co-issues with the next k-step's ds_reads (register double-set,
//   statically indexed); compiler's auto-lgkmcnt handles the reg dependencies.
//   Safety: lgkm(0)+B1 retires all reads of buf[cur] in every wave before the
//   stage(T+2) overwrite; per-wave vmcnt(4) then B2 makes T+1's DMA globally visible.
//
// LDS XOR swizzle (verified in the 16x16 version): tile row r stores its four 16B
// K-chunks permuted by key=(r>>1)&3, applied on the GLOBAL fetch address (the DMA
// cannot scatter); fragment reads un-swizzle with the same key. Wave b128 reads land
// on the uniform-minimum bank distribution (8 lanes per 4-bank group).
__global__ __launch_bounds__(256, 3) void gemm_i8(const signed char* __restrict__ xq,
                                                  const signed char* __restrict__ w8,
                                                  const float* __restrict__ sx,
                                                  const float* __restrict__ sw,
                                                  const float* __restrict__ bias,
                                                  float* __restrict__ out,
                                                  int M, int N, int K) {
    __shared__ signed char As[2][8192];   // 128 rows x 64B
    __shared__ signed char Bs[2][8192];

    const int tid  = threadIdx.x;
    const int lane = tid & 63;
    const int wave = tid >> 6;
    const int m_off = (wave >> 1) * 64;
    const int n_off = (wave & 1) * 64;
    const int m_block = blockIdx.y * 128;
    const int n_block = blockIdx.x * 128;
    const int NT = K >> 6;

    v16i acc[2][2];
#pragma unroll
    for (int mi = 0; mi < 2; ++mi)
#pragma unroll
        for (int ni = 0; ni < 2; ++ni)
#pragma unroll
            for (int e = 0; e < 16; ++e) acc[mi][ni][e] = 0;

    // staging map: thread t -> LDS slot (row t>>2, chunk t&3); fetches swizzled
    // global chunk (t&3)^((t>>3)&3). Key invariant under +64 rows.
    const int sr = tid >> 2;
    const int sc = ((tid & 3) ^ ((sr >> 1) & 3)) * 16;
    const signed char* aG = xq + (size_t)(m_block + sr) * K + sc;
    const signed char* bG = w8 + (size_t)(n_block + sr) * K + sc;
    const int ldst = wave * 1024;  // + lane*16 implicit in the DMA

    auto stage = [&](int Tt, int b) {
        const size_t ko = (size_t)Tt << 6;
        gll16(aG + ko,                    &As[b][ldst]);
        gll16(aG + ko + ((size_t)K << 6), &As[b][ldst + 4096]);  // rows +64
        gll16(bG + ko,                    &Bs[b][ldst]);
        gll16(bG + ko + ((size_t)K << 6), &Bs[b][ldst + 4096]);
    };

    // 32x32x32 fragment read: lane l -> row (l&31), k-bytes ks*32+(l>>5)*16.
    // Logical chunk c = ks*2+hi lives at physical chunk c^key, key=(row>>1)&3.
    const int rl  = lane & 31;
    const int hi  = lane >> 5;
    const int key = (rl >> 1) & 3;
    const int ck0 = (hi ^ key) * 16;        // k-step 0
    const int ck1 = ((2 + hi) ^ key) * 16;  // k-step 1
    const int arow = (m_off + rl) * 64;
    const int brow = (n_off + rl) * 64;

    // prologue: T0 -> buf0, T1 -> buf1; wait T0 resident (T1's 4 stay in flight)
    stage(0, 0);
    stage(1, 1);
    asm volatile("s_waitcnt vmcnt(4)" ::: "memory");
    __builtin_amdgcn_s_barrier();

    v4i a0, a1, b0, b1;      // current k-step fragments
    v4i na0, na1, nb0, nb1;  // next k-step fragments
    a0 = *(const v4i*)(As[0] + arow + ck0);
    a1 = *(const v4i*)(As[0] + arow + 2048 + ck0);
    b0 = *(const v4i*)(Bs[0] + brow + ck0);
    b1 = *(const v4i*)(Bs[0] + brow + 2048 + ck0);

    for (int T = 0; T < NT; ++T) {
        const int cur = T & 1;
        const signed char* Ac = As[cur];
        const signed char* Bc = Bs[cur];
        // issue ks1 reads; they overlap the ks0 MFMAs below
        na0 = *(const v4i*)(Ac + arow + ck1);
        na1 = *(const v4i*)(Ac + arow + 2048 + ck1);
        nb0 = *(const v4i*)(Bc + brow + ck1);
        nb1 = *(const v4i*)(Bc + brow + 2048 + ck1);

        acc[0][0] = __builtin_amdgcn_mfma_i32_32x32x32_i8(a0, b0, acc[0][0], 0, 0, 0);
        acc[0][1] = __builtin_amdgcn_mfma_i32_32x32x32_i8(a0, b1, acc[0][1], 0, 0, 0);
        acc[1][0] = __builtin_amdgcn_mfma_i32_32x32x32_i8(a1, b0, acc[1][0], 0, 0, 0);
        acc[1][1] = __builtin_amdgcn_mfma_i32_32x32x32_i8(a1, b1, acc[1][1], 0, 0, 0);

        asm volatile("s_waitcnt lgkmcnt(0)" ::: "memory");  // all buf[cur] reads retired
        __builtin_amdgcn_s_barrier();                       // B1: safe to overwrite buf[cur]

        if (T + 2 < NT) stage(T + 2, cur);

        if (T + 1 < NT) {
            if (T + 2 < NT)
                asm volatile("s_waitcnt vmcnt(4)" ::: "memory");  // T+1 resident; T+2 in flight
            else
                asm volatile("s_waitcnt vmcnt(0)" ::: "memory");  // tail: nothing newer
            __builtin_amdgcn_s_barrier();                   // B2: T+1 LDS visible
            const signed char* An = As[cur ^ 1];
            const signed char* Bn = Bs[cur ^ 1];
            // issue T+1 ks0 reads; they overlap the ks1 MFMAs below
            a0 = *(const v4i*)(An + arow + ck0);
            a1 = *(const v4i*)(An + arow + 2048 + ck0);
            b0 = *(const v4i*)(Bn + brow + ck0);
            b1 = *(const v4i*)(Bn + brow + 2048 + ck0);
        }

        acc[0][0] = __builtin_amdgcn_mfma_i32_32x32x32_i8(na0, nb0, acc[0][0], 0, 0, 0);
        acc[0][1] = __builtin_amdgcn_mfma_i32_32x32x32_i8(na0, nb1, acc[0][1], 0, 0, 0);
        acc[1][0] = __builtin_amdgcn_mfma_i32_32x32x32_i8(na1, nb0, acc[1][0], 0, 0, 0);
        acc[1][1] = __builtin_amdgcn_mfma_i32_32x32x32_i8(na1, nb1, acc[1][1], 0, 0, 0);
    }

    // epilogue: 32x32 C/D layout: col = lane&31, row = (reg&3) + 8*(reg>>2) + 4*(lane>>5)
#pragma unroll
    for (int mi = 0; mi < 2; ++mi)
#pragma unroll
        for (int q = 0; q < 4; ++q) {
            const int rbase = m_block + m_off + mi * 32 + q * 8 + hi * 4;
            float sxv[4];
#pragma unroll
            for (int r = 0; r < 4; ++r) sxv[r] = sx[rbase + r];  // pad rows: sx=0
#pragma unroll
            for (int ni = 0; ni < 2; ++ni) {
                const int col = n_block + n_off + ni * 32 + rl;
                const float swv = sw[col];
                const float bv  = bias[col];
#pragma unroll
                for (int r = 0; r < 4; ++r) {
                    const int row = rbase + r;
                    if (row < M)
                        out[(size_t)row * N + col] = (float)acc[mi][ni][q * 4 + r] * sxv[r] * swv + bv;
                }
            }
        }
}

extern "C" void kernel_launch(void* const* d_in, const int* in_sizes, int n_in,
                              void* d_out, int out_size, void* d_ws, size_t ws_size,
                              hipStream_t stream) {
    const float* x       = (const float*)d_in[0];
    const int*   w_int   = (const int*)d_in[1];
    const float* scale_w = (const float*)d_in[2];
    const float* bias    = (const float*)d_in[3];
    float* out = (float*)d_out;

    const int D_OUT = in_sizes[2];             // 2560
    const int D_IN  = in_sizes[1] / D_OUT;     // 1024
    const int M     = in_sizes[0] / D_IN;      // 18464
    const int Mpad  = ((M + 127) / 128) * 128; // 18560

    // workspace layout (all 16B-aligned):
    signed char* xq = (signed char*)d_ws;                      // Mpad * D_IN  int8
    signed char* w8 = xq + (size_t)Mpad * D_IN;                // D_OUT * D_IN int8
    float*       sx = (float*)(w8 + (size_t)D_OUT * D_IN);     // Mpad floats

    quant_x<<<Mpad, 256, 0, stream>>>(x, xq, sx, M);
    const int n4 = D_OUT * D_IN / 4;
    conv_w<<<(n4 + 255) / 256, 256, 0, stream>>>(w_int, w8, n4);
    dim3 grid(D_OUT / 128, Mpad / 128);  // (20, 145): x-major sweeps N for one M-panel -> A-tile L2 reuse
    gemm_i8<<<grid, dim3(256, 1, 1), 0, stream>>>(xq, w8, sx, scale_w, bias, out, M, D_OUT, D_IN);
}